// Round 13
// baseline (1407.352 us; speedup 1.0000x reference)
//
#include <hip/hip_runtime.h>
#include <math.h>

// LSTMEncoder N=2048, T=128, H=256. 4-way column-split, W register-resident.
// 256 blocks x 1024 thr (16 waves). Block (q4=bid>>6, g=bid&63): rows g*32..+31,
// h-cols q4*64..+63. Wave w owns cols w*4..+3 (lane l16=c*4+q: col c, gate q).
// W slice = 9 frags (8 K-tiles W_hh + folded x/bias tile) = 36 VGPR, loaded once.
// R13 exchange: SELF-TAGGED 8B units {lo=2 bf16 h (col pair), hi=tag=t} written
// by ONE atomic global_store_dwordx2 sc0 sc1 -> no data drain, no separate tag
// store, publish is fire-and-forget. 1024 units/block/step; consumer = 1 unit
// per thread per partner (3 probes). Publish + out stores come DIRECT from
// registers via ds_swizzle xor-4 (column-neighbor exchange) -> phase F reads no
// LDS -> ONE barrier per step. LDS h double-buffered (GEMM reads pw, EW writes
// cw). EW: quad-transpose via templated ds_swizzle, own-row-only transcendentals.

#define TT 128
#define NH 256

typedef __attribute__((ext_vector_type(4))) float f32x4;
typedef __attribute__((ext_vector_type(8))) short s16x8;
typedef union { uint4 u4; s16x8 s; unsigned u[4]; } frag_u;

// ws layout (bytes):
//   wsW [0, 589824)         : 576 frags x 64 lanes x 16B
//   pub [589824, +4194304)  : [2 parity][256 bid][1024 units x 8B]
#define OFF_PUB    589824
#define PUB_STRIDE 8192
#define PUB_BYTES  (2 * 256 * PUB_STRIDE)

__device__ __forceinline__ unsigned short f2bf(float x) {
    unsigned u = __float_as_uint(x);
    return (unsigned short)((u + 0x7FFFu + ((u >> 16) & 1u)) >> 16);
}
__device__ __forceinline__ float bf2f(unsigned b) {
    return __uint_as_float(b << 16);
}

template<int PAT>
__device__ __forceinline__ float qswz(float x) {
    return __int_as_float(__builtin_amdgcn_ds_swizzle(__float_as_int(x), PAT));
}

__global__ void prep(const float* __restrict__ W_emb, const float* __restrict__ b_emb,
                     const float* __restrict__ W_ih,  const float* __restrict__ W_hh,
                     const float* __restrict__ b_ih,  const float* __restrict__ b_hh,
                     unsigned short* __restrict__ wsW)
{
    int tid = blockIdx.x * 256 + threadIdx.x;   // 0..36863
    if (tid >= 36864) return;
    int l    = tid & 63;
    int fid  = tid >> 6;          // 0..575
    int kt   = fid % 9;
    int cg16 = fid / 9;           // n-tile id 0..63  (== q4*16 + w)
    int l16  = l & 15, lg = l >> 4;
    int c    = l16 >> 2, q = l16 & 3;
    int col  = cg16 * 4 + c;      // h column
    int grow = q * 256 + col;     // gate row (i,f,g,o blocks of 256)
    union { unsigned short u16[8]; uint4 v; } pk;
    if (kt < 8) {
        int k0 = kt * 32 + lg * 8;
        const float* src = &W_hh[grow * 256 + k0];
        #pragma unroll
        for (int i = 0; i < 8; ++i) pk.u16[i] = f2bf(src[i]);
    } else {
        #pragma unroll
        for (int i = 0; i < 8; ++i) pk.u16[i] = 0;
        if (lg == 0) {
            float accf[6] = {0.f, 0.f, 0.f, 0.f, 0.f, 0.f};
            float accb = 0.f;
            for (int e = 0; e < 256; ++e) {
                float wv = W_ih[grow * 256 + e];
                accb += wv * b_emb[e];
                #pragma unroll
                for (int f = 0; f < 6; ++f) accf[f] += wv * W_emb[e * 6 + f];
            }
            #pragma unroll
            for (int f = 0; f < 6; ++f) pk.u16[f] = f2bf(accf[f]);
            pk.u16[6] = f2bf(accb + b_ih[grow] + b_hh[grow]);
        }
    }
    *reinterpret_cast<uint4*>(&wsW[(size_t)fid * 512 + l * 8]) = pk.v;
}

__device__ __forceinline__ float sigmoidf_(float x) { return 1.f / (1.f + __expf(-x)); }
__device__ __forceinline__ float tanhf_(float x) {
    float e = __expf(-2.f * fabsf(x));
    float r = (1.f - e) / (1.f + e);
    return copysignf(r, x);
}

__device__ __forceinline__ unsigned long long ld8_dev(const void* p) {  // fused load+wait
    unsigned long long v;
    asm volatile("global_load_dwordx2 %0, %1, off sc0 sc1\n\ts_waitcnt vmcnt(0)"
                 : "=v"(v) : "v"(p) : "memory");
    return v;
}
__device__ __forceinline__ void st8_dev(void* p, unsigned long long v) { // atomic 8B
    asm volatile("global_store_dwordx2 %0, %1, off sc0 sc1" :: "v"(p), "v"(v) : "memory");
}

// quad-transpose gather: from acc (4 gate regs, quad rows) pick this lane's row
__device__ __forceinline__ void qgather(const f32x4& acc, bool qb0, bool qb1, float X[4]) {
    float g0, g1, g2, g3, x01, x23;
    g0 = qswz<0x8000>(acc[0]); g1 = qswz<0x8000>(acc[1]);
    g2 = qswz<0x8000>(acc[2]); g3 = qswz<0x8000>(acc[3]);
    x01 = qb0 ? g1 : g0; x23 = qb0 ? g3 : g2; X[0] = qb1 ? x23 : x01;
    g0 = qswz<0x8055>(acc[0]); g1 = qswz<0x8055>(acc[1]);
    g2 = qswz<0x8055>(acc[2]); g3 = qswz<0x8055>(acc[3]);
    x01 = qb0 ? g1 : g0; x23 = qb0 ? g3 : g2; X[1] = qb1 ? x23 : x01;
    g0 = qswz<0x80AA>(acc[0]); g1 = qswz<0x80AA>(acc[1]);
    g2 = qswz<0x80AA>(acc[2]); g3 = qswz<0x80AA>(acc[3]);
    x01 = qb0 ? g1 : g0; x23 = qb0 ? g3 : g2; X[2] = qb1 ? x23 : x01;
    g0 = qswz<0x80FF>(acc[0]); g1 = qswz<0x80FF>(acc[1]);
    g2 = qswz<0x80FF>(acc[2]); g3 = qswz<0x80FF>(acc[3]);
    x01 = qb0 ? g1 : g0; x23 = qb0 ? g3 : g2; X[3] = qb1 ? x23 : x01;
}

__global__ __launch_bounds__(1024, 4)
void lstm_main(const float* __restrict__ xin, const unsigned short* __restrict__ wsW,
               float* __restrict__ out, char* __restrict__ pub)
{
    // double-buffered by t parity: GEMM reads [pw], EW writes [cw]
    __shared__ __align__(16) unsigned short hsh[2][32][264];

    const int tid = threadIdx.x;
    const int w   = tid >> 6, l = tid & 63;
    const int l16 = l & 15,  lg = l >> 4;
    const int c   = l16 >> 2, q = l16 & 3;
    const bool qb0 = (q & 1), qb1 = (q & 2);
    const int bid = blockIdx.x;
    const int q4  = bid >> 6;            // column quarter 0..3
    const int g   = bid & 63;            // row group
    const int n0  = g * 32;
    const int j   = q4 * 64 + w * 4 + c; // lane's global h column
    const int cg16 = q4 * 16 + w;
    const int R0  = lg * 4 + q;          // m0 row (in-block)
    const int R1  = 16 + R0;             // m1 row
    const bool evc = ((c & 1) == 0);

    // ---- persistent W: 9 frags = 36 VGPR, volatile-asm loads (no remat) ----
    frag_u Wf[9];
    #pragma unroll
    for (int kt = 0; kt < 9; ++kt) {
        const unsigned short* p = &wsW[(size_t)(cg16 * 9 + kt) * 512 + l * 8];
        asm volatile("global_load_dwordx4 %0, %1, off" : "=v"(Wf[kt].u4) : "v"(p));
    }
    asm volatile("s_waitcnt vmcnt(0)" ::: "memory");

    float cm0 = 0.f, cm1 = 0.f;          // cell state rows R0 / R1

    // staging geometry: this thread handles unit tid of each of 3 partners
    const int pp0 = 0 + (0 >= q4);
    const int pp1 = pp0 + 1 + (pp0 + 1 == q4);
    const int pp2 = pp1 + 1 + (pp1 + 1 == q4);
    const int sr  = tid >> 5;            // unit row 0..31
    const int sd  = tid & 31;            // unit col-pair 0..31
    // publish geometry (even-c lanes): unit index per m-tile
    const int updx = w * 2 + (c >> 1);   // col-pair within quarter

    for (int t = 0; t < TT; ++t) {
        const int want = t - 1;
        const unsigned wtag = (unsigned)want;
        const int pw = want & 1;         // read-parity (h(t-1))
        const int cw = t & 1;            // write-parity (h(t))
        unsigned long long v0 = 0, v1 = 0, v2 = 0;
        const char *s0 = nullptr, *s1 = nullptr, *s2 = nullptr;

        // ---- A. issue 3 partner probes (no wait) ----
        if (t > 0) {
            const char* base = pub + (size_t)pw * 256 * PUB_STRIDE + (size_t)tid * 8;
            s0 = base + (size_t)(g + 64 * pp0) * PUB_STRIDE;
            s1 = base + (size_t)(g + 64 * pp1) * PUB_STRIDE;
            s2 = base + (size_t)(g + 64 * pp2) * PUB_STRIDE;
            asm volatile("global_load_dwordx2 %0, %1, off sc0 sc1" : "=v"(v0) : "v"(s0) : "memory");
            asm volatile("global_load_dwordx2 %0, %1, off sc0 sc1" : "=v"(v1) : "v"(s1) : "memory");
            asm volatile("global_load_dwordx2 %0, %1, off sc0 sc1" : "=v"(v2) : "v"(s2) : "memory");
        }

        // ---- B. x/bias A-frags (cached loads; overlap probe flight) ----
        frag_u xa0, xa1;
        xa0.u4 = (uint4){0u, 0u, 0u, 0u};
        xa1.u4 = (uint4){0u, 0u, 0u, 0u};
        if (lg == 0) {
            union { unsigned short u16[8]; uint4 v; } pk;
            const float* xp0 = xin + ((size_t)(n0 + l16) * TT + t) * 6;
            #pragma unroll
            for (int f = 0; f < 6; ++f) pk.u16[f] = f2bf(xp0[f]);
            pk.u16[6] = 0x3F80; pk.u16[7] = 0;
            xa0.u4 = pk.v;
            const float* xp1 = xin + ((size_t)(n0 + 16 + l16) * TT + t) * 6;
            #pragma unroll
            for (int f = 0; f < 6; ++f) pk.u16[f] = f2bf(xp1[f]);
            pk.u16[6] = 0x3F80; pk.u16[7] = 0;
            xa1.u4 = pk.v;
        }

        // ---- C. one check; s_sleep-backoff retries only for stale lanes ----
        if (t > 0) {
            asm volatile("s_waitcnt vmcnt(0)" ::: "memory");
            __builtin_amdgcn_sched_barrier(0);   // rule #18
            bool ok0 = ((unsigned)(v0 >> 32) == wtag);
            bool ok1 = ((unsigned)(v1 >> 32) == wtag);
            bool ok2 = ((unsigned)(v2 >> 32) == wtag);
            int it = 0;
            while (__ballot(!(ok0 && ok1 && ok2)) != 0ull) {
                __builtin_amdgcn_s_sleep(1);
                if (!ok0) { v0 = ld8_dev(s0); ok0 = ((unsigned)(v0 >> 32) == wtag); }
                if (!ok1) { v1 = ld8_dev(s1); ok1 = ((unsigned)(v1 >> 32) == wtag); }
                if (!ok2) { v2 = ld8_dev(s2); ok2 = ((unsigned)(v2 >> 32) == wtag); }
                if (++it > (1 << 14)) break;     // fail loud via absmax, not hang
            }
            // stage the 3 data dwords into LDS (2 bf16 each)
            *reinterpret_cast<unsigned*>(&hsh[pw][sr][pp0 * 64 + 2 * sd]) = (unsigned)v0;
            *reinterpret_cast<unsigned*>(&hsh[pw][sr][pp1 * 64 + 2 * sd]) = (unsigned)v1;
            *reinterpret_cast<unsigned*>(&hsh[pw][sr][pp2 * 64 + 2 * sd]) = (unsigned)v2;
        }
        __syncthreads();   // BAR1 (the only barrier): h(t-1) complete in hsh[pw]

        // ---- D. recurrent GEMM + x-tile (reads hsh[pw] only) ----
        f32x4 acc0 = (f32x4){0.f, 0.f, 0.f, 0.f};
        f32x4 acc1 = (f32x4){0.f, 0.f, 0.f, 0.f};
        if (t > 0) {
            #pragma unroll
            for (int kt = 0; kt < 8; ++kt) {
                s16x8 a0 = *reinterpret_cast<const s16x8*>(&hsh[pw][l16     ][kt * 32 + lg * 8]);
                s16x8 a1 = *reinterpret_cast<const s16x8*>(&hsh[pw][16 + l16][kt * 32 + lg * 8]);
                acc0 = __builtin_amdgcn_mfma_f32_16x16x32_bf16(a0, Wf[kt].s, acc0, 0, 0, 0);
                acc1 = __builtin_amdgcn_mfma_f32_16x16x32_bf16(a1, Wf[kt].s, acc1, 0, 0, 0);
            }
        }
        acc0 = __builtin_amdgcn_mfma_f32_16x16x32_bf16(xa0.s, Wf[8].s, acc0, 0, 0, 0);
        acc1 = __builtin_amdgcn_mfma_f32_16x16x32_bf16(xa1.s, Wf[8].s, acc1, 0, 0, 0);

        // ---- E. quad-transpose gather + elementwise for OWN row q only ----
        float hn0, hn1;
        {
            float X[4];
            qgather(acc0, qb0, qb1, X);
            float cn = fmaf(sigmoidf_(X[1]), cm0, sigmoidf_(X[0]) * tanhf_(X[2]));
            cm0 = cn;
            hn0 = sigmoidf_(X[3]) * tanhf_(cn);
            qgather(acc1, qb0, qb1, X);
            cn = fmaf(sigmoidf_(X[1]), cm1, sigmoidf_(X[0]) * tanhf_(X[2]));
            cm1 = cn;
            hn1 = sigmoidf_(X[3]) * tanhf_(cn);
        }
        const unsigned us0 = f2bf(hn0), us1 = f2bf(hn1);
        // own h(t) -> LDS buf cw (consumed only by GEMM(t+1), fenced by BAR1)
        hsh[cw][R0][j] = (unsigned short)us0;
        hsh[cw][R1][j] = (unsigned short)us1;

        // ---- F. publish + out DIRECT from registers (no LDS read, no BAR3) ----
        // column-neighbor exchange: lane <-> lane^4 (c <-> c^1)
        float hp0 = qswz<0x101F>(hn0);
        float hp1 = qswz<0x101F>(hn1);
        if (evc) {
            if (t < TT - 1) {
                const unsigned long long tagbits = ((unsigned long long)(unsigned)t) << 32;
                unsigned d0 = (us0 & 0xffffu) | ((unsigned)f2bf(hp0) << 16);
                unsigned d1 = (us1 & 0xffffu) | ((unsigned)f2bf(hp1) << 16);
                char* dstb = pub + ((size_t)cw * 256 + bid) * PUB_STRIDE;
                st8_dev(dstb + (size_t)(R0 * 32 + updx) * 8, (unsigned long long)d0 | tagbits);
                st8_dev(dstb + (size_t)(R1 * 32 + updx) * 8, (unsigned long long)d1 | tagbits);
            }
            *reinterpret_cast<float2*>(&out[((size_t)(n0 + R0) * TT + t) * NH + j])
                = make_float2(hn0, hp0);
            *reinterpret_cast<float2*>(&out[((size_t)(n0 + R1) * TT + t) * NH + j])
                = make_float2(hn1, hp1);
        }
        // no further barrier: next iter's staging writes hsh[cw] PARTNER cols
        // (disjoint from own cols written above); GEMM(t+1) fenced by BAR1(t+1).
    }
}

extern "C" void kernel_launch(void* const* d_in, const int* in_sizes, int n_in,
                              void* d_out, int out_size, void* d_ws, size_t ws_size,
                              hipStream_t stream)
{
    const float* xin   = (const float*)d_in[0];
    const float* W_emb = (const float*)d_in[1];
    const float* b_emb = (const float*)d_in[2];
    const float* W_ih  = (const float*)d_in[3];
    const float* W_hh  = (const float*)d_in[4];
    const float* b_ih  = (const float*)d_in[5];
    const float* b_hh  = (const float*)d_in[6];
    float* out = (float*)d_out;

    unsigned short* wsW = (unsigned short*)d_ws;
    char* pub = (char*)d_ws + OFF_PUB;

    (void)hipMemsetAsync(pub, 0xFF, PUB_BYTES, stream);  // tags -> -1 (never valid)
    prep<<<144, 256, 0, stream>>>(W_emb, b_emb, W_ih, W_hh, b_ih, b_hh, wsW);
    lstm_main<<<256, 1024, 0, stream>>>(xin, wsW, out, pub);
}

// Round 14
// 780.160 us; speedup vs baseline: 1.8039x; 1.8039x over previous
//
#include <hip/hip_runtime.h>
#include <math.h>

// LSTMEncoder N=2048, T=128, H=256. S=4 column-split + 2-GROUP PIPELINE.
// 256 blocks x 1024 thr (16 waves). Block (q4=bid>>6, g63=bid&63): rows
// n0=g63*32..+31 split into group A (rows 0-15) and B (rows 16-31); h-cols
// q4*64..+63. Wave w owns n-tile q4*16+w per group (lane l16=c*4+q).
// W slice = 9 frags (8 K-tiles W_hh + folded x/bias) = 36 VGPR, loaded once.
// Exchange: atomic 8B self-tagged units {lo=2 bf16 (col pair), hi=tag=t}, one
// global_store_dwordx2 sc0 sc1. PIPELINE: probes for group G are issued one
// half-phase EARLY (during the other group's GEMM/EW) so the MALL round-trip
// is off the critical path. 2 barriers/step. Probe load = 1/thread/phase
// (+1 for tid<512). EW: quad-transpose ds_swizzle, own-row transcendentals.

#define TT 128
#define NH 256

typedef __attribute__((ext_vector_type(4))) float f32x4;
typedef __attribute__((ext_vector_type(8))) short s16x8;
typedef union { uint4 u4; s16x8 s; unsigned u[4]; } frag_u;

// ws layout (bytes):
//   wsW [0, 589824)         : 576 frags x 64 lanes x 16B
//   pub [589824, +4194304)  : [2 parity][256 bid][1024 units x 8B]
//                              unit = grp*512 + row*32 + colpair
#define OFF_PUB    589824
#define PUB_STRIDE 8192
#define PUB_BYTES  (2 * 256 * PUB_STRIDE)

__device__ __forceinline__ unsigned short f2bf(float x) {
    unsigned u = __float_as_uint(x);
    return (unsigned short)((u + 0x7FFFu + ((u >> 16) & 1u)) >> 16);
}

template<int PAT>
__device__ __forceinline__ float qswz(float x) {
    return __int_as_float(__builtin_amdgcn_ds_swizzle(__float_as_int(x), PAT));
}

__global__ void prep(const float* __restrict__ W_emb, const float* __restrict__ b_emb,
                     const float* __restrict__ W_ih,  const float* __restrict__ W_hh,
                     const float* __restrict__ b_ih,  const float* __restrict__ b_hh,
                     unsigned short* __restrict__ wsW)
{
    int tid = blockIdx.x * 256 + threadIdx.x;   // 0..36863
    if (tid >= 36864) return;
    int l    = tid & 63;
    int fid  = tid >> 6;          // 0..575
    int kt   = fid % 9;
    int cg16 = fid / 9;           // n-tile id 0..63  (== q4*16 + w)
    int l16  = l & 15, lg = l >> 4;
    int c    = l16 >> 2, q = l16 & 3;
    int col  = cg16 * 4 + c;      // h column
    int grow = q * 256 + col;     // gate row (i,f,g,o blocks of 256)
    union { unsigned short u16[8]; uint4 v; } pk;
    if (kt < 8) {
        int k0 = kt * 32 + lg * 8;
        const float* src = &W_hh[grow * 256 + k0];
        #pragma unroll
        for (int i = 0; i < 8; ++i) pk.u16[i] = f2bf(src[i]);
    } else {
        #pragma unroll
        for (int i = 0; i < 8; ++i) pk.u16[i] = 0;
        if (lg == 0) {
            float accf[6] = {0.f, 0.f, 0.f, 0.f, 0.f, 0.f};
            float accb = 0.f;
            for (int e = 0; e < 256; ++e) {
                float wv = W_ih[grow * 256 + e];
                accb += wv * b_emb[e];
                #pragma unroll
                for (int f = 0; f < 6; ++f) accf[f] += wv * W_emb[e * 6 + f];
            }
            #pragma unroll
            for (int f = 0; f < 6; ++f) pk.u16[f] = f2bf(accf[f]);
            pk.u16[6] = f2bf(accb + b_ih[grow] + b_hh[grow]);
        }
    }
    *reinterpret_cast<uint4*>(&wsW[(size_t)fid * 512 + l * 8]) = pk.v;
}

__device__ __forceinline__ float sigmoidf_(float x) { return 1.f / (1.f + __expf(-x)); }
__device__ __forceinline__ float tanhf_(float x) {
    float e = __expf(-2.f * fabsf(x));
    float r = (1.f - e) / (1.f + e);
    return copysignf(r, x);
}

__device__ __forceinline__ unsigned long long ld8_dev(const void* p) {  // fused load+wait
    unsigned long long v;
    asm volatile("global_load_dwordx2 %0, %1, off sc0 sc1\n\ts_waitcnt vmcnt(0)"
                 : "=v"(v) : "v"(p) : "memory");
    return v;
}
__device__ __forceinline__ void st8_dev(void* p, unsigned long long v) { // atomic 8B
    asm volatile("global_store_dwordx2 %0, %1, off sc0 sc1" :: "v"(p), "v"(v) : "memory");
}

// quad-transpose gather: from acc (4 gate regs, quad rows) pick this lane's row
__device__ __forceinline__ void qgather(const f32x4& acc, bool qb0, bool qb1, float X[4]) {
    float g0, g1, g2, g3, x01, x23;
    g0 = qswz<0x8000>(acc[0]); g1 = qswz<0x8000>(acc[1]);
    g2 = qswz<0x8000>(acc[2]); g3 = qswz<0x8000>(acc[3]);
    x01 = qb0 ? g1 : g0; x23 = qb0 ? g3 : g2; X[0] = qb1 ? x23 : x01;
    g0 = qswz<0x8055>(acc[0]); g1 = qswz<0x8055>(acc[1]);
    g2 = qswz<0x8055>(acc[2]); g3 = qswz<0x8055>(acc[3]);
    x01 = qb0 ? g1 : g0; x23 = qb0 ? g3 : g2; X[1] = qb1 ? x23 : x01;
    g0 = qswz<0x80AA>(acc[0]); g1 = qswz<0x80AA>(acc[1]);
    g2 = qswz<0x80AA>(acc[2]); g3 = qswz<0x80AA>(acc[3]);
    x01 = qb0 ? g1 : g0; x23 = qb0 ? g3 : g2; X[2] = qb1 ? x23 : x01;
    g0 = qswz<0x80FF>(acc[0]); g1 = qswz<0x80FF>(acc[1]);
    g2 = qswz<0x80FF>(acc[2]); g3 = qswz<0x80FF>(acc[3]);
    x01 = qb0 ? g1 : g0; x23 = qb0 ? g3 : g2; X[3] = qb1 ? x23 : x01;
}

__global__ __launch_bounds__(1024, 4)
void lstm_main(const float* __restrict__ xin, const unsigned short* __restrict__ wsW,
               float* __restrict__ out, char* __restrict__ pub)
{
    // [parity][group][16 rows][264]: GEMM reads [pw][g], EW writes [cw][g]
    __shared__ __align__(16) unsigned short hsh[2][2][16][264];

    const int tid = threadIdx.x;
    const int w   = tid >> 6, l = tid & 63;
    const int l16 = l & 15,  lg = l >> 4;
    const int c   = l16 >> 2, q = l16 & 3;
    const bool qb0 = (q & 1), qb1 = (q & 2);
    const int bid = blockIdx.x;
    const int q4  = bid >> 6;            // column quarter 0..3
    const int g63 = bid & 63;            // row group
    const int n0  = g63 * 32;
    const int j   = q4 * 64 + w * 4 + c; // lane's in-NH h column
    const int cg16 = q4 * 16 + w;
    const int R0  = lg * 4 + q;          // lane's row within a 16-row group
    const bool evc = ((c & 1) == 0);

    // ---- persistent W: 9 frags = 36 VGPR, volatile-asm loads (no remat) ----
    frag_u Wf[9];
    #pragma unroll
    for (int kt = 0; kt < 9; ++kt) {
        const unsigned short* p = &wsW[(size_t)(cg16 * 9 + kt) * 512 + l * 8];
        asm volatile("global_load_dwordx4 %0, %1, off" : "=v"(Wf[kt].u4) : "v"(p));
    }
    asm volatile("s_waitcnt vmcnt(0)" ::: "memory");

    float cmA = 0.f, cmB = 0.f;          // cell state (row n0+R0 / n0+16+R0)

    // partner quarters (ordinals -> actual)
    const int pp0 = 0 + (0 >= q4);
    const int pp1 = pp0 + 1 + (pp0 + 1 == q4);
    const int pp2 = pp1 + 1 + (pp1 + 1 == q4);
    // probe geometry: probe0 = unit (tid&511) of partner (tid>>9 ? pp1 : pp0);
    //                 probe1 (tid<512) = unit tid of partner pp2
    const int pq0 = (tid >> 9) ? pp1 : pp0;
    const int u0  = tid & 511;
    const bool has1 = (tid < 512);
    const int u1  = tid;
    // staging targets (constant): row, col within partner quarter
    const int sr0 = u0 >> 5, sc0 = pq0 * 64 + 2 * (u0 & 31);
    const int sr1 = u1 >> 5, sc1 = pp2 * 64 + 2 * (u1 & 31);
    // publish unit (even-c lanes): row*32 + colpair
    const int upub = R0 * 32 + w * 2 + (c >> 1);

    unsigned long long pv0 = 0, pv1 = 0;
    const char *ps0 = nullptr, *ps1 = nullptr;

    for (int t = 0; t < TT; ++t) {
        const int want = t - 1;
        const unsigned wtag = (unsigned)want;
        const int pw = want & 1;
        const int cw = t & 1;

        // =================== GROUP A (rows n0 .. n0+15) ===================
        // x/bias A-frag for group A
        frag_u xa; xa.u4 = (uint4){0u, 0u, 0u, 0u};
        if (lg == 0) {
            union { unsigned short u16[8]; uint4 v; } pk;
            const float* xp = xin + ((size_t)(n0 + l16) * TT + t) * 6;
            #pragma unroll
            for (int f = 0; f < 6; ++f) pk.u16[f] = f2bf(xp[f]);
            pk.u16[6] = 0x3F80; pk.u16[7] = 0;
            xa.u4 = pk.v;
        }
        if (t > 0) {
            // probes for A(t-1) were issued during B-phase of t-1
            asm volatile("s_waitcnt vmcnt(0)" ::: "memory");
            __builtin_amdgcn_sched_barrier(0);
            bool ok0 = ((unsigned)(pv0 >> 32) == wtag);
            bool ok1 = (!has1) || ((unsigned)(pv1 >> 32) == wtag);
            int it = 0;
            while (__ballot(!(ok0 && ok1)) != 0ull) {
                __builtin_amdgcn_s_sleep(1);
                if (!ok0) { pv0 = ld8_dev(ps0); ok0 = ((unsigned)(pv0 >> 32) == wtag); }
                if (!ok1) { pv1 = ld8_dev(ps1); ok1 = ((unsigned)(pv1 >> 32) == wtag); }
                if (++it > (1 << 14)) break;    // fail loud via absmax, not hang
            }
            *reinterpret_cast<unsigned*>(&hsh[pw][0][sr0][sc0]) = (unsigned)pv0;
            if (has1)
                *reinterpret_cast<unsigned*>(&hsh[pw][0][sr1][sc1]) = (unsigned)pv1;
        }
        __syncthreads();   // BAR_A: group-A h(t-1) complete in hsh[pw][0]

        // issue group-B probes for (t-1); flight hides under GEMM_A/EW_A
        if (t > 0) {
            const char* base = pub + (size_t)pw * 256 * PUB_STRIDE;
            ps0 = base + (size_t)(pq0 * 64 + g63) * PUB_STRIDE + (size_t)(512 + u0) * 8;
            asm volatile("global_load_dwordx2 %0, %1, off sc0 sc1"
                         : "=v"(pv0) : "v"(ps0) : "memory");
            if (has1) {
                ps1 = base + (size_t)(pp2 * 64 + g63) * PUB_STRIDE + (size_t)(512 + u1) * 8;
                asm volatile("global_load_dwordx2 %0, %1, off sc0 sc1"
                             : "=v"(pv1) : "v"(ps1) : "memory");
            }
        }

        // GEMM_A + x-tile
        f32x4 acc = (f32x4){0.f, 0.f, 0.f, 0.f};
        if (t > 0) {
            #pragma unroll
            for (int kt = 0; kt < 8; ++kt) {
                s16x8 a = *reinterpret_cast<const s16x8*>(&hsh[pw][0][l16][kt * 32 + lg * 8]);
                acc = __builtin_amdgcn_mfma_f32_16x16x32_bf16(a, Wf[kt].s, acc, 0, 0, 0);
            }
        }
        acc = __builtin_amdgcn_mfma_f32_16x16x32_bf16(xa.s, Wf[8].s, acc, 0, 0, 0);

        // EW_A
        {
            float X[4];
            qgather(acc, qb0, qb1, X);
            float cn = fmaf(sigmoidf_(X[1]), cmA, sigmoidf_(X[0]) * tanhf_(X[2]));
            cmA = cn;
            float hn = sigmoidf_(X[3]) * tanhf_(cn);
            unsigned us = f2bf(hn);
            hsh[cw][0][R0][j] = (unsigned short)us;      // own cols for GEMM(t+1)
            float hp = qswz<0x101F>(hn);                 // col-neighbor c^1
            if (evc) {
                if (t < TT - 1) {
                    unsigned d = (us & 0xffffu) | ((unsigned)f2bf(hp) << 16);
                    char* dst = pub + ((size_t)cw * 256 + bid) * PUB_STRIDE
                                    + (size_t)upub * 8;
                    st8_dev(dst, (unsigned long long)d | ((unsigned long long)(unsigned)t << 32));
                }
                *reinterpret_cast<float2*>(&out[((size_t)(n0 + R0) * TT + t) * NH + j])
                    = make_float2(hn, hp);
            }
        }

        // =================== GROUP B (rows n0+16 .. n0+31) ===================
        frag_u xb; xb.u4 = (uint4){0u, 0u, 0u, 0u};
        if (lg == 0) {
            union { unsigned short u16[8]; uint4 v; } pk;
            const float* xp = xin + ((size_t)(n0 + 16 + l16) * TT + t) * 6;
            #pragma unroll
            for (int f = 0; f < 6; ++f) pk.u16[f] = f2bf(xp[f]);
            pk.u16[6] = 0x3F80; pk.u16[7] = 0;
            xb.u4 = pk.v;
        }
        if (t > 0) {
            asm volatile("s_waitcnt vmcnt(0)" ::: "memory");   // B probes + A stores
            __builtin_amdgcn_sched_barrier(0);
            bool ok0 = ((unsigned)(pv0 >> 32) == wtag);
            bool ok1 = (!has1) || ((unsigned)(pv1 >> 32) == wtag);
            int it = 0;
            while (__ballot(!(ok0 && ok1)) != 0ull) {
                __builtin_amdgcn_s_sleep(1);
                if (!ok0) { pv0 = ld8_dev(ps0); ok0 = ((unsigned)(pv0 >> 32) == wtag); }
                if (!ok1) { pv1 = ld8_dev(ps1); ok1 = ((unsigned)(pv1 >> 32) == wtag); }
                if (++it > (1 << 14)) break;
            }
            *reinterpret_cast<unsigned*>(&hsh[pw][1][sr0][sc0]) = (unsigned)pv0;
            if (has1)
                *reinterpret_cast<unsigned*>(&hsh[pw][1][sr1][sc1]) = (unsigned)pv1;
        }
        __syncthreads();   // BAR_B: group-B h(t-1) complete in hsh[pw][1]

        // issue group-A probes for step t+1 (tag t, parity cw); hides under GEMM_B
        if (t < TT - 1) {
            const char* base = pub + (size_t)cw * 256 * PUB_STRIDE;
            ps0 = base + (size_t)(pq0 * 64 + g63) * PUB_STRIDE + (size_t)u0 * 8;
            asm volatile("global_load_dwordx2 %0, %1, off sc0 sc1"
                         : "=v"(pv0) : "v"(ps0) : "memory");
            if (has1) {
                ps1 = base + (size_t)(pp2 * 64 + g63) * PUB_STRIDE + (size_t)u1 * 8;
                asm volatile("global_load_dwordx2 %0, %1, off sc0 sc1"
                             : "=v"(pv1) : "v"(ps1) : "memory");
            }
        }

        // GEMM_B + x-tile
        f32x4 accb = (f32x4){0.f, 0.f, 0.f, 0.f};
        if (t > 0) {
            #pragma unroll
            for (int kt = 0; kt < 8; ++kt) {
                s16x8 a = *reinterpret_cast<const s16x8*>(&hsh[pw][1][l16][kt * 32 + lg * 8]);
                accb = __builtin_amdgcn_mfma_f32_16x16x32_bf16(a, Wf[kt].s, accb, 0, 0, 0);
            }
        }
        accb = __builtin_amdgcn_mfma_f32_16x16x32_bf16(xb.s, Wf[8].s, accb, 0, 0, 0);

        // EW_B
        {
            float X[4];
            qgather(accb, qb0, qb1, X);
            float cn = fmaf(sigmoidf_(X[1]), cmB, sigmoidf_(X[0]) * tanhf_(X[2]));
            cmB = cn;
            float hn = sigmoidf_(X[3]) * tanhf_(cn);
            unsigned us = f2bf(hn);
            hsh[cw][1][R0][j] = (unsigned short)us;
            float hp = qswz<0x101F>(hn);
            if (evc) {
                if (t < TT - 1) {
                    unsigned d = (us & 0xffffu) | ((unsigned)f2bf(hp) << 16);
                    char* dst = pub + ((size_t)cw * 256 + bid) * PUB_STRIDE
                                    + (size_t)(512 + upub) * 8;
                    st8_dev(dst, (unsigned long long)d | ((unsigned long long)(unsigned)t << 32));
                }
                *reinterpret_cast<float2*>(&out[((size_t)(n0 + 16 + R0) * TT + t) * NH + j])
                    = make_float2(hn, hp);
            }
        }
        // no extra barrier: next A-staging writes [pw(t+1)=cw][0] partner cols;
        // EW_B wrote [cw][1] own cols (disjoint plane); GEMM reads fenced by BARs.
    }
}

extern "C" void kernel_launch(void* const* d_in, const int* in_sizes, int n_in,
                              void* d_out, int out_size, void* d_ws, size_t ws_size,
                              hipStream_t stream)
{
    const float* xin   = (const float*)d_in[0];
    const float* W_emb = (const float*)d_in[1];
    const float* b_emb = (const float*)d_in[2];
    const float* W_ih  = (const float*)d_in[3];
    const float* W_hh  = (const float*)d_in[4];
    const float* b_ih  = (const float*)d_in[5];
    const float* b_hh  = (const float*)d_in[6];
    float* out = (float*)d_out;

    unsigned short* wsW = (unsigned short*)d_ws;
    char* pub = (char*)d_ws + OFF_PUB;

    (void)hipMemsetAsync(pub, 0xFF, PUB_BYTES, stream);  // tags -> -1 (never valid)
    prep<<<144, 256, 0, stream>>>(W_emb, b_emb, W_ih, W_hh, b_ih, b_hh, wsW);
    lstm_main<<<256, 1024, 0, stream>>>(xin, wsW, out, pub);
}

// Round 17
// 753.725 us; speedup vs baseline: 1.8672x; 1.0351x over previous
//
#include <hip/hip_runtime.h>
#include <math.h>

// LSTMEncoder N=2048, T=128, H=256. S=4 column-split + 2-group pipeline +
// counted-vmcnt discipline (no vmcnt(0) drains in steady state; raw s_barrier
// with lgkmcnt-only). 256 blocks x 1024 thr. Block (q4=bid>>6, g63=bid&63):
// rows g63*32..+31 (groups A/B of 16), h-cols q4*64..+63. W slice = 9 frags
// = 36 VGPR (volatile-asm loads). Exchange: atomic 8B self-tagged units
// {2 bf16, tag}. Steady phase issues EXACTLY 5 vmem ops in fixed order
// [probes(2), xfrag(1), out(1), pub(1)]; check = s_waitcnt vmcnt(2) (probes+
// xfrag landed; stores never waited). Barriers never drain vmcnt.
// R17 fix vs R16: out stores are OWN-QUARTER only (1 f32/thread, uniform) —
// R16's full-row epilogue wrote never-exchanged partner cols of h(127)
// (stale h(125)) -> absmax 0.7. Own-quarter coverage is exact by q4 split.

#define TT 128
#define NH 256

typedef __attribute__((ext_vector_type(4))) float f32x4;
typedef __attribute__((ext_vector_type(8))) short s16x8;
typedef unsigned long long u64;
typedef union { uint4 u4; s16x8 s; unsigned u[4]; } frag_u;

// ws layout (bytes):
//   wsW [0, 589824)            : 576 frags x 64 lanes x 16B
//   xab [589824, 4784128)      : [2048][128] uint4 x-A-frags (6 bf16,1.0,0)
//   pub [4784128, 8978432)     : [2 parity][256 bid][1024 units x 8B]
#define OFF_XAB    589824
#define OFF_PUB    4784128
#define PUB_STRIDE 8192
#define PUB_BYTES  (2 * 256 * PUB_STRIDE)

__device__ __forceinline__ unsigned short f2bf(float x) {
    unsigned u = __float_as_uint(x);
    return (unsigned short)((u + 0x7FFFu + ((u >> 16) & 1u)) >> 16);
}
__device__ __forceinline__ float bf2f(unsigned b) {
    return __uint_as_float(b << 16);
}

template<int PAT>
__device__ __forceinline__ float qswz(float x) {
    return __int_as_float(__builtin_amdgcn_ds_swizzle(__float_as_int(x), PAT));
}

__global__ void prep(const float* __restrict__ xin,
                     const float* __restrict__ W_emb, const float* __restrict__ b_emb,
                     const float* __restrict__ W_ih,  const float* __restrict__ W_hh,
                     const float* __restrict__ b_ih,  const float* __restrict__ b_hh,
                     unsigned short* __restrict__ wsW, uint4* __restrict__ xab)
{
    int tid = blockIdx.x * 256 + threadIdx.x;
    if (tid < 36864) {
        int l    = tid & 63;
        int fid  = tid >> 6;          // 0..575
        int kt   = fid % 9;
        int cg16 = fid / 9;
        int l16  = l & 15, lg = l >> 4;
        int c    = l16 >> 2, q = l16 & 3;
        int col  = cg16 * 4 + c;
        int grow = q * 256 + col;
        union { unsigned short u16[8]; uint4 v; } pk;
        if (kt < 8) {
            int k0 = kt * 32 + lg * 8;
            const float* src = &W_hh[grow * 256 + k0];
            #pragma unroll
            for (int i = 0; i < 8; ++i) pk.u16[i] = f2bf(src[i]);
        } else {
            #pragma unroll
            for (int i = 0; i < 8; ++i) pk.u16[i] = 0;
            if (lg == 0) {
                float accf[6] = {0.f, 0.f, 0.f, 0.f, 0.f, 0.f};
                float accb = 0.f;
                for (int e = 0; e < 256; ++e) {
                    float wv = W_ih[grow * 256 + e];
                    accb += wv * b_emb[e];
                    #pragma unroll
                    for (int f = 0; f < 6; ++f) accf[f] += wv * W_emb[e * 6 + f];
                }
                #pragma unroll
                for (int f = 0; f < 6; ++f) pk.u16[f] = f2bf(accf[f]);
                pk.u16[6] = f2bf(accb + b_ih[grow] + b_hh[grow]);
            }
        }
        *reinterpret_cast<uint4*>(&wsW[(size_t)fid * 512 + l * 8]) = pk.v;
    } else if (tid < 36864 + 262144) {
        int u = tid - 36864;          // row*128 + t
        int row = u >> 7, t = u & 127;
        const float* xp = xin + ((size_t)row * TT + t) * 6;
        union { unsigned short u16[8]; uint4 v; } pk;
        #pragma unroll
        for (int f = 0; f < 6; ++f) pk.u16[f] = f2bf(xp[f]);
        pk.u16[6] = 0x3F80; pk.u16[7] = 0;
        xab[u] = pk.v;
    }
}

__device__ __forceinline__ float sigmoidf_(float x) { return 1.f / (1.f + __expf(-x)); }
__device__ __forceinline__ float tanhf_(float x) {
    float e = __expf(-2.f * fabsf(x));
    float r = (1.f - e) / (1.f + e);
    return copysignf(r, x);
}

__device__ __forceinline__ u64 ld8_dev(const void* p) {   // retry path only
    u64 v;
    asm volatile("global_load_dwordx2 %0, %1, off sc0 sc1\n\ts_waitcnt vmcnt(0)"
                 : "=v"(v) : "v"(p) : "memory");
    return v;
}
__device__ __forceinline__ void st8_dev(void* p, u64 v) {  // pub (MALL)
    asm volatile("global_store_dwordx2 %0, %1, off sc0 sc1" :: "v"(p), "v"(v) : "memory");
}
__device__ __forceinline__ void st4_plain(void* p, unsigned v) { // out (L2 cached)
    asm volatile("global_store_dword %0, %1, off" :: "v"(p), "v"(v) : "memory");
}
// raw barrier: LDS-complete only, NO vmcnt drain
__device__ __forceinline__ void sync_lds() {
    asm volatile("s_waitcnt lgkmcnt(0)" ::: "memory");
    __builtin_amdgcn_s_barrier();
    __builtin_amdgcn_sched_barrier(0);
}

__device__ __forceinline__ void qgather(const f32x4& acc, bool qb0, bool qb1, float X[4]) {
    float g0, g1, g2, g3, x01, x23;
    g0 = qswz<0x8000>(acc[0]); g1 = qswz<0x8000>(acc[1]);
    g2 = qswz<0x8000>(acc[2]); g3 = qswz<0x8000>(acc[3]);
    x01 = qb0 ? g1 : g0; x23 = qb0 ? g3 : g2; X[0] = qb1 ? x23 : x01;
    g0 = qswz<0x8055>(acc[0]); g1 = qswz<0x8055>(acc[1]);
    g2 = qswz<0x8055>(acc[2]); g3 = qswz<0x8055>(acc[3]);
    x01 = qb0 ? g1 : g0; x23 = qb0 ? g3 : g2; X[1] = qb1 ? x23 : x01;
    g0 = qswz<0x80AA>(acc[0]); g1 = qswz<0x80AA>(acc[1]);
    g2 = qswz<0x80AA>(acc[2]); g3 = qswz<0x80AA>(acc[3]);
    x01 = qb0 ? g1 : g0; x23 = qb0 ? g3 : g2; X[2] = qb1 ? x23 : x01;
    g0 = qswz<0x80FF>(acc[0]); g1 = qswz<0x80FF>(acc[1]);
    g2 = qswz<0x80FF>(acc[2]); g3 = qswz<0x80FF>(acc[3]);
    x01 = qb0 ? g1 : g0; x23 = qb0 ? g3 : g2; X[3] = qb1 ? x23 : x01;
}

__device__ __forceinline__ float ew_step(const f32x4& acc, float& cm, bool qb0, bool qb1) {
    float X[4];
    qgather(acc, qb0, qb1, X);
    float cn = fmaf(sigmoidf_(X[1]), cm, sigmoidf_(X[0]) * tanhf_(X[2]));
    cm = cn;
    return sigmoidf_(X[3]) * tanhf_(cn);
}

__global__ __launch_bounds__(1024, 4)
void lstm_main(const unsigned short* __restrict__ wsW, const uint4* __restrict__ xab,
               float* __restrict__ out, char* __restrict__ pub)
{
    __shared__ __align__(16) unsigned short hsh[2][2][16][264];

    const int tid = threadIdx.x;
    const int w   = tid >> 6, l = tid & 63;
    const int l16 = l & 15,  lg = l >> 4;
    const int c   = l16 >> 2, q = l16 & 3;
    const bool qb0 = (q & 1), qb1 = (q & 2);
    const int bid = blockIdx.x;
    const int q4  = bid >> 6;
    const int g63 = bid & 63;
    const int n0  = g63 * 32;
    const int j   = q4 * 64 + w * 4 + c;
    const int cg16 = q4 * 16 + w;
    const int R0  = lg * 4 + q;
    const bool evc = ((c & 1) == 0);

    // ---- persistent W ----
    frag_u Wf[9];
    #pragma unroll
    for (int kt = 0; kt < 9; ++kt) {
        const unsigned short* p = &wsW[(size_t)(cg16 * 9 + kt) * 512 + l * 8];
        asm volatile("global_load_dwordx4 %0, %1, off" : "=v"(Wf[kt].u4) : "v"(p));
    }
    asm volatile("s_waitcnt vmcnt(0)" ::: "memory");

    float cmA = 0.f, cmB = 0.f;

    // partners / probe geometry
    const int pp0 = 0 + (0 >= q4);
    const int pp1 = pp0 + 1 + (pp0 + 1 == q4);
    const int pp2 = pp1 + 1 + (pp1 + 1 == q4);
    const bool has1 = (tid < 512);
    const int pq0 = has1 ? pp0 : pp1;
    const int pq1 = has1 ? pp2 : pp1;      // dup of pq0 for tid>=512
    const int u0  = tid & 511;
    const int u1  = tid & 511;
    const int sr0 = u0 >> 5, sc0 = pq0 * 64 + 2 * (u0 & 31);
    const int sr1 = u1 >> 5, sc1 = pq1 * 64 + 2 * (u1 & 31);
    const int upub = R0 * 32 + w * 2 + (c >> 1);
    const int orow = tid >> 6;             // out row (== wave id, 0..15)
    const int ocol = q4 * 64 + (tid & 63); // out col (own quarter, f32 idx)

    u64 pv0 = 0, pv1 = 0;
    const char *ps0 = nullptr, *ps1 = nullptr;
    frag_u xfA, xfB;

    // ================= PROLOGUE (t = 0) =================
    {
        uint4 xA0 = xab[(size_t)(n0 + l16) * TT + 0];
        uint4 xB0 = xab[(size_t)(n0 + 16 + l16) * TT + 0];
        frag_u xa; xa.u4 = xA0;
        frag_u xb; xb.u4 = xB0;
        f32x4 z = (f32x4){0.f, 0.f, 0.f, 0.f};
        f32x4 accA = __builtin_amdgcn_mfma_f32_16x16x32_bf16(xa.s, Wf[8].s, z, 0, 0, 0);
        f32x4 accB = __builtin_amdgcn_mfma_f32_16x16x32_bf16(xb.s, Wf[8].s, z, 0, 0, 0);
        float hnA = ew_step(accA, cmA, qb0, qb1);
        float hnB = ew_step(accB, cmB, qb0, qb1);
        unsigned usA = f2bf(hnA), usB = f2bf(hnB);
        hsh[0][0][R0][j] = (unsigned short)usA;
        hsh[0][1][R0][j] = (unsigned short)usB;
        float hpA = qswz<0x101F>(hnA);
        float hpB = qswz<0x101F>(hnB);
        unsigned dA = (usA & 0xffffu) | ((unsigned)f2bf(hpA) << 16);
        unsigned dB = (usB & 0xffffu) | ((unsigned)f2bf(hpB) << 16);

        asm volatile("s_waitcnt vmcnt(0)" ::: "memory");   // reset counting

        // tail, fixed order (5 ops): [probe, probe, xfA, pubA, pubB]
        ps0 = pub + (size_t)(pq0 * 64 + g63) * PUB_STRIDE + (size_t)u0 * 8;
        ps1 = pub + (size_t)(pq1 * 64 + g63) * PUB_STRIDE + (size_t)u1 * 8;
        asm volatile("global_load_dwordx2 %0, %1, off sc0 sc1" : "=v"(pv0) : "v"(ps0) : "memory");
        asm volatile("global_load_dwordx2 %0, %1, off sc0 sc1" : "=v"(pv1) : "v"(ps1) : "memory");
        const uint4* xp = xab + (size_t)(n0 + l16) * TT + 1;
        asm volatile("global_load_dwordx4 %0, %1, off" : "=v"(xfA.u4) : "v"(xp) : "memory");
        if (evc) {
            char* dstb = pub + (size_t)bid * PUB_STRIDE;
            st8_dev(dstb + (size_t)upub * 8, (u64)dA);           // tag 0
            st8_dev(dstb + (size_t)(512 + upub) * 8, (u64)dB);   // tag 0
        }
    }

    // ================= MAIN LOOP t = 1..127 =================
    for (int t = 1; t < TT; ++t) {
        const int pw = (t - 1) & 1;
        const int cw = t & 1;
        const unsigned want = (unsigned)(t - 1);

        // ---------------- PHASE A ----------------
        {
            asm volatile("s_waitcnt vmcnt(2)" ::: "memory");
            __builtin_amdgcn_sched_barrier(0);
            asm volatile("" : "+v"(pv0), "+v"(pv1));
            asm volatile("" : "+v"(xfA.s));
            bool ok0 = ((unsigned)(pv0 >> 32) == want);
            bool ok1 = ((unsigned)(pv1 >> 32) == want);
            int it = 0;
            while (__ballot(!(ok0 && ok1)) != 0ull) {
                __builtin_amdgcn_s_sleep(1);
                if (!ok0) { pv0 = ld8_dev(ps0); ok0 = ((unsigned)(pv0 >> 32) == want); }
                if (!ok1) { pv1 = ld8_dev(ps1); ok1 = ((unsigned)(pv1 >> 32) == want); }
                if (++it > (1 << 12)) break;   // fail loud via absmax
            }
            *reinterpret_cast<unsigned*>(&hsh[pw][0][sr0][sc0]) = (unsigned)pv0;
            if (has1)
                *reinterpret_cast<unsigned*>(&hsh[pw][0][sr1][sc1]) = (unsigned)pv1;
            sync_lds();

            // issue PHASE-B probes: group B (units +512), parity pw, tag t-1
            {
                const char* base = pub + (size_t)pw * 256 * PUB_STRIDE;
                ps0 = base + (size_t)(pq0 * 64 + g63) * PUB_STRIDE + (size_t)(512 + u0) * 8;
                ps1 = base + (size_t)(pq1 * 64 + g63) * PUB_STRIDE + (size_t)(512 + u1) * 8;
                asm volatile("global_load_dwordx2 %0, %1, off sc0 sc1" : "=v"(pv0) : "v"(ps0) : "memory");
                asm volatile("global_load_dwordx2 %0, %1, off sc0 sc1" : "=v"(pv1) : "v"(ps1) : "memory");
            }
            // xfrag for PHASE B (rows n0+16+l16, time t)
            {
                const uint4* xp = xab + (size_t)(n0 + 16 + l16) * TT + t;
                asm volatile("global_load_dwordx4 %0, %1, off" : "=v"(xfB.u4) : "v"(xp) : "memory");
            }
            // out(t-1) group A, OWN quarter only (1 f32/thread, wave-contig)
            {
                unsigned hv = (unsigned)hsh[pw][0][orow][ocol];
                st4_plain(out + ((size_t)(n0 + orow) * TT + (t - 1)) * NH + ocol,
                          hv << 16);
            }
            // GEMM_A
            f32x4 acc = (f32x4){0.f, 0.f, 0.f, 0.f};
            #pragma unroll
            for (int kt = 0; kt < 8; ++kt) {
                s16x8 a = *reinterpret_cast<const s16x8*>(&hsh[pw][0][l16][kt * 32 + lg * 8]);
                acc = __builtin_amdgcn_mfma_f32_16x16x32_bf16(a, Wf[kt].s, acc, 0, 0, 0);
            }
            acc = __builtin_amdgcn_mfma_f32_16x16x32_bf16(xfA.s, Wf[8].s, acc, 0, 0, 0);
            // EW_A + publish
            float hn = ew_step(acc, cmA, qb0, qb1);
            unsigned us = f2bf(hn);
            hsh[cw][0][R0][j] = (unsigned short)us;
            float hp = qswz<0x101F>(hn);
            if (evc) {
                unsigned d = (us & 0xffffu) | ((unsigned)f2bf(hp) << 16);
                char* dst = pub + ((size_t)cw * 256 + bid) * PUB_STRIDE + (size_t)upub * 8;
                st8_dev(dst, (u64)d | ((u64)(unsigned)t << 32));
            }
        }

        // ---------------- PHASE B ----------------
        {
            asm volatile("s_waitcnt vmcnt(2)" ::: "memory");
            __builtin_amdgcn_sched_barrier(0);
            asm volatile("" : "+v"(pv0), "+v"(pv1));
            asm volatile("" : "+v"(xfB.s));
            bool ok0 = ((unsigned)(pv0 >> 32) == want);
            bool ok1 = ((unsigned)(pv1 >> 32) == want);
            int it = 0;
            while (__ballot(!(ok0 && ok1)) != 0ull) {
                __builtin_amdgcn_s_sleep(1);
                if (!ok0) { pv0 = ld8_dev(ps0); ok0 = ((unsigned)(pv0 >> 32) == want); }
                if (!ok1) { pv1 = ld8_dev(ps1); ok1 = ((unsigned)(pv1 >> 32) == want); }
                if (++it > (1 << 12)) break;
            }
            *reinterpret_cast<unsigned*>(&hsh[pw][1][sr0][sc0]) = (unsigned)pv0;
            if (has1)
                *reinterpret_cast<unsigned*>(&hsh[pw][1][sr1][sc1]) = (unsigned)pv1;
            sync_lds();

            // issue PHASE-A(t+1) probes: group A (units +0), parity cw, tag t
            {
                const char* base = pub + (size_t)cw * 256 * PUB_STRIDE;
                ps0 = base + (size_t)(pq0 * 64 + g63) * PUB_STRIDE + (size_t)u0 * 8;
                ps1 = base + (size_t)(pq1 * 64 + g63) * PUB_STRIDE + (size_t)u1 * 8;
                asm volatile("global_load_dwordx2 %0, %1, off sc0 sc1" : "=v"(pv0) : "v"(ps0) : "memory");
                asm volatile("global_load_dwordx2 %0, %1, off sc0 sc1" : "=v"(pv1) : "v"(ps1) : "memory");
            }
            // xfrag for PHASE A(t+1) (rows n0+l16, time t+1; at t=127 reads 16B
            // past xab end = start of pub — allocated, value unused)
            {
                const uint4* xp = xab + (size_t)(n0 + l16) * TT + (t + 1);
                asm volatile("global_load_dwordx4 %0, %1, off" : "=v"(xfA.u4) : "v"(xp) : "memory");
            }
            // out(t-1) group B, OWN quarter only
            {
                unsigned hv = (unsigned)hsh[pw][1][orow][ocol];
                st4_plain(out + ((size_t)(n0 + 16 + orow) * TT + (t - 1)) * NH + ocol,
                          hv << 16);
            }
            // GEMM_B
            f32x4 acc = (f32x4){0.f, 0.f, 0.f, 0.f};
            #pragma unroll
            for (int kt = 0; kt < 8; ++kt) {
                s16x8 a = *reinterpret_cast<const s16x8*>(&hsh[pw][1][l16][kt * 32 + lg * 8]);
                acc = __builtin_amdgcn_mfma_f32_16x16x32_bf16(a, Wf[kt].s, acc, 0, 0, 0);
            }
            acc = __builtin_amdgcn_mfma_f32_16x16x32_bf16(xfB.s, Wf[8].s, acc, 0, 0, 0);
            // EW_B + publish
            float hn = ew_step(acc, cmB, qb0, qb1);
            unsigned us = f2bf(hn);
            hsh[cw][1][R0][j] = (unsigned short)us;
            float hp = qswz<0x101F>(hn);
            if (evc) {
                unsigned d = (us & 0xffffu) | ((unsigned)f2bf(hp) << 16);
                char* dst = pub + ((size_t)cw * 256 + bid) * PUB_STRIDE + (size_t)(512 + upub) * 8;
                st8_dev(dst, (u64)d | ((u64)(unsigned)t << 32));
            }
        }
    }

    // ================= EPILOGUE: out(127), OWN quarter only =================
    sync_lds();   // h(127) own cols (written by EW this step) visible block-wide
    {
        unsigned hvA = (unsigned)hsh[1][0][orow][ocol];
        unsigned hvB = (unsigned)hsh[1][1][orow][ocol];
        st4_plain(out + ((size_t)(n0 + orow) * TT + (TT - 1)) * NH + ocol, hvA << 16);
        st4_plain(out + ((size_t)(n0 + 16 + orow) * TT + (TT - 1)) * NH + ocol, hvB << 16);
    }
}

extern "C" void kernel_launch(void* const* d_in, const int* in_sizes, int n_in,
                              void* d_out, int out_size, void* d_ws, size_t ws_size,
                              hipStream_t stream)
{
    const float* xin   = (const float*)d_in[0];
    const float* W_emb = (const float*)d_in[1];
    const float* b_emb = (const float*)d_in[2];
    const float* W_ih  = (const float*)d_in[3];
    const float* W_hh  = (const float*)d_in[4];
    const float* b_ih  = (const float*)d_in[5];
    const float* b_hh  = (const float*)d_in[6];
    float* out = (float*)d_out;

    unsigned short* wsW = (unsigned short*)d_ws;
    uint4* xab = (uint4*)((char*)d_ws + OFF_XAB);
    char* pub  = (char*)d_ws + OFF_PUB;

    (void)hipMemsetAsync(pub, 0xFF, PUB_BYTES, stream);  // tags -> never-valid
    prep<<<1168, 256, 0, stream>>>(xin, W_emb, b_emb, W_ih, W_hh, b_ih, b_hh, wsW, xab);
    lstm_main<<<256, 1024, 0, stream>>>(wsW, xab, out, pub);
}